// Round 1
// baseline (165.197 us; speedup 1.0000x reference)
//
#include <hip/hip_runtime.h>

#define DI __device__ __forceinline__

typedef __bf16 bf16x8 __attribute__((ext_vector_type(8)));
typedef float  f32x4  __attribute__((ext_vector_type(4)));
typedef unsigned short u16;
typedef unsigned int   u32;

constexpr int BATCH  = 2;
constexpr int NNODE  = 4097;          // 64*64 grid + 1 global token
constexpr int M_REAL = BATCH * NNODE; // 8194
constexpr int M_PAD  = 8320;          // 65 * 128
constexpr int KDIM   = 512;

DI float bf2f(u16 u)  { return __uint_as_float(((u32)u) << 16); }
DI float bflo(u32 v)  { return __uint_as_float(v << 16); }
DI float bfhi(u32 v)  { return __uint_as_float(v & 0xffff0000u); }
DI u16   f2bf(float f) {
  u32 u = __float_as_uint(f);
  u32 r = (u + 0x7fffu + ((u >> 16) & 1u)) >> 16;   // RNE
  return (u16)r;
}

DI void gload_lds16(const void* g, void* l) {
  __builtin_amdgcn_global_load_lds(
      (const __attribute__((address_space(1))) u32*)g,
      (__attribute__((address_space(3))) u32*)l, 16, 0, 0);
}

// ---------------------------------------------------------------- prep ----
// region A: x [8194][512] f32 -> Xp [8320][512] bf16 (pad rows zeroed)
// region B: Wq|Wk|Wv -> Wqkv [1536][512] bf16
// region C: Wo -> Wob [512][512] bf16
constexpr int NCH_X  = M_PAD * KDIM / 8;   // 532480
constexpr int NCH_WQ = 1536 * KDIM / 8;    // 98304
constexpr int NCH_WO = 512 * KDIM / 8;     // 32768

__global__ __launch_bounds__(256) void prep(
    const float* __restrict__ x,  const float* __restrict__ wq,
    const float* __restrict__ wk, const float* __restrict__ wv,
    const float* __restrict__ wo,
    u16* __restrict__ Xp, u16* __restrict__ Wqkv, u16* __restrict__ Wob) {
  int idx = blockIdx.x * 256 + threadIdx.x;
  const float* src = nullptr;
  u16* dst = nullptr;
  bool zero = false;
  if (idx < NCH_X) {
    int row = idx >> 6;                      // 64 chunks per 512-col row
    dst = Xp + (size_t)idx * 8;
    if (row < M_REAL) src = x + (size_t)idx * 8; else zero = true;
  } else if (idx < NCH_X + NCH_WQ) {
    int t = idx - NCH_X;
    int row = t >> 6;
    dst = Wqkv + (size_t)t * 8;
    const float* W = row < 512 ? wq : (row < 1024 ? wk : wv);
    src = W + ((size_t)(row & 511) << 9) + ((t & 63) * 8);
  } else if (idx < NCH_X + NCH_WQ + NCH_WO) {
    int t = idx - NCH_X - NCH_WQ;
    dst = Wob + (size_t)t * 8;
    src = wo + (size_t)t * 8;
  } else {
    return;
  }
  u32 o[4];
  if (zero) {
    o[0] = o[1] = o[2] = o[3] = 0u;
  } else {
    float4 f0 = ((const float4*)src)[0];
    float4 f1 = ((const float4*)src)[1];
    o[0] = (u32)f2bf(f0.x) | ((u32)f2bf(f0.y) << 16);
    o[1] = (u32)f2bf(f0.z) | ((u32)f2bf(f0.w) << 16);
    o[2] = (u32)f2bf(f1.x) | ((u32)f2bf(f1.y) << 16);
    o[3] = (u32)f2bf(f1.z) | ((u32)f2bf(f1.w) << 16);
  }
  uint4 v; v.x = o[0]; v.y = o[1]; v.z = o[2]; v.w = o[3];
  *(uint4*)dst = v;
}

// ---------------------------------------------------------------- GEMM ----
// C[m,n] = sum_k A[m,k] * B[n,k]   (A: [M_PAD][512] bf16, B: [N][512] bf16)
// 128x128 tile, BK=64, 4 waves (2x2), each wave 64x64 via 4x4 16x16x32 MFMAs.
template <int N, bool OUT_F32>
__global__ __launch_bounds__(256) void gemm_bt(
    const u16* __restrict__ A, const u16* __restrict__ B,
    u16* __restrict__ Cb, float* __restrict__ Cf) {
  __shared__ __align__(16) u16 As[128 * 64];
  __shared__ __align__(16) u16 Bs[128 * 64];
  const int tid  = threadIdx.x;
  const int lane = tid & 63;
  const int wm = ((tid >> 6) >> 1) * 64;
  const int wn = ((tid >> 6) & 1) * 64;
  const int m0 = blockIdx.x * 128;
  const int n0 = blockIdx.y * 128;

  f32x4 acc[4][4] = {};

  const int rstg = tid >> 3;
  const int cstg = (tid & 7) * 8;
  const u16* Ag = A + (size_t)(m0 + rstg) * KDIM + cstg;
  const u16* Bg = B + (size_t)(n0 + rstg) * KDIM + cstg;
  char* AsB = (char*)As + tid * 16;
  char* BsB = (char*)Bs + tid * 16;

  for (int kt = 0; kt < KDIM; kt += 64) {
#pragma unroll
    for (int inst = 0; inst < 4; ++inst) {
      gload_lds16(Ag + (size_t)inst * 32 * KDIM + kt, AsB + inst * 4096);
      gload_lds16(Bg + (size_t)inst * 32 * KDIM + kt, BsB + inst * 4096);
    }
    __syncthreads();
#pragma unroll
    for (int kc = 0; kc < 2; ++kc) {
      const int ko = kc * 32 + (lane >> 4) * 8;
      bf16x8 af[4], bfr[4];
#pragma unroll
      for (int mi = 0; mi < 4; ++mi)
        af[mi] = *(const bf16x8*)&As[(wm + mi * 16 + (lane & 15)) * 64 + ko];
#pragma unroll
      for (int ni = 0; ni < 4; ++ni)
        bfr[ni] = *(const bf16x8*)&Bs[(wn + ni * 16 + (lane & 15)) * 64 + ko];
#pragma unroll
      for (int mi = 0; mi < 4; ++mi)
#pragma unroll
        for (int ni = 0; ni < 4; ++ni)
          acc[mi][ni] = __builtin_amdgcn_mfma_f32_16x16x32_bf16(
              af[mi], bfr[ni], acc[mi][ni], 0, 0, 0);
    }
    __syncthreads();
  }

  const int cr = (lane >> 4) * 4;
  const int cc = lane & 15;
#pragma unroll
  for (int mi = 0; mi < 4; ++mi) {
#pragma unroll
    for (int j = 0; j < 4; ++j) {
      const int row = m0 + wm + mi * 16 + cr + j;
      if (OUT_F32 && row >= M_REAL) continue;
#pragma unroll
      for (int ni = 0; ni < 4; ++ni) {
        const int col = n0 + wn + ni * 16 + cc;
        if constexpr (OUT_F32)
          Cf[(size_t)row * N + col] = acc[mi][ni][j];
        else
          Cb[(size_t)row * N + col] = f2bf(acc[mi][ni][j]);
      }
    }
  }
}

// ------------------------------------------------------------ attention ----
// QKV: [M_PAD][1536] bf16  (q cols 0..511, k 512..1023, v 1024..1535)
// O:   [M_PAD][512]  bf16
// blocks 0..15: dense global-token row (b,h).  blocks 16..: sparse rows,
// one wave per (b, grid node), <=6 keys: {global 0, self, 4-neighborhood}.
__global__ __launch_bounds__(256) void attn(const u16* __restrict__ QKV,
                                            u16* __restrict__ O) {
  const int tid = threadIdx.x;
  if (blockIdx.x < 16) {
    __shared__ float sc[NNODE];
    __shared__ float qs[64];
    __shared__ float red[256];
    const int b = blockIdx.x >> 3;
    const int h = blockIdx.x & 7;
    const size_t base = (size_t)b * NNODE;
    if (tid < 64) qs[tid] = bf2f(QKV[base * 1536 + h * 64 + tid]);
    __syncthreads();
    for (int j = tid; j < NNODE; j += 256) {
      const uint4* kp4 = (const uint4*)(QKV + (base + j) * 1536 + 512 + h * 64);
      float a = 0.f;
#pragma unroll
      for (int q8 = 0; q8 < 8; ++q8) {
        uint4 kv = kp4[q8];
        int d = q8 * 8;
        a += qs[d+0]*bflo(kv.x) + qs[d+1]*bfhi(kv.x)
           + qs[d+2]*bflo(kv.y) + qs[d+3]*bfhi(kv.y)
           + qs[d+4]*bflo(kv.z) + qs[d+5]*bfhi(kv.z)
           + qs[d+6]*bflo(kv.w) + qs[d+7]*bfhi(kv.w);
      }
      sc[j] = a * 0.125f;
    }
    __syncthreads();
    float mx = -1e30f;
    for (int j = tid; j < NNODE; j += 256) mx = fmaxf(mx, sc[j]);
    red[tid] = mx;
    __syncthreads();
    for (int s = 128; s > 0; s >>= 1) {
      if (tid < s) red[tid] = fmaxf(red[tid], red[tid + s]);
      __syncthreads();
    }
    mx = red[0];
    __syncthreads();
    float sm = 0.f;
    for (int j = tid; j < NNODE; j += 256) {
      float e = __expf(sc[j] - mx);
      sc[j] = e;
      sm += e;
    }
    red[tid] = sm;
    __syncthreads();
    for (int s = 128; s > 0; s >>= 1) {
      if (tid < s) red[tid] += red[tid + s];
      __syncthreads();
    }
    const float inv = 1.f / red[0];
    __syncthreads();
    const int d = tid & 63, grp = tid >> 6;
    const u16* vp = QKV + 1024 + h * 64 + d;
    float a0 = 0, a1 = 0, a2 = 0, a3 = 0;
    int j = grp;
    for (; j + 12 < NNODE; j += 16) {
      a0 += sc[j]      * bf2f(vp[(base + j) * 1536]);
      a1 += sc[j + 4]  * bf2f(vp[(base + j + 4) * 1536]);
      a2 += sc[j + 8]  * bf2f(vp[(base + j + 8) * 1536]);
      a3 += sc[j + 12] * bf2f(vp[(base + j + 12) * 1536]);
    }
    for (; j < NNODE; j += 4) a0 += sc[j] * bf2f(vp[(base + j) * 1536]);
    red[tid] = a0 + a1 + a2 + a3;
    __syncthreads();
    if (tid < 64) {
      float o = (red[tid] + red[tid + 64] + red[tid + 128] + red[tid + 192]) * inv;
      O[base * 512 + h * 64 + tid] = f2bf(o);
    }
    return;
  }

  // ---- sparse rows: one wave per (b, node) ----
  const int wid  = (blockIdx.x - 16) * 4 + (tid >> 6);  // 0..8191
  const int lane = tid & 63;
  const int b = wid >> 12;
  const int g = wid & 4095;
  const int i = g + 1;
  const int r = g >> 6, c = g & 63;
  const size_t base = (size_t)b * NNODE;

  int  jn[6];
  bool vd[6];
  jn[0] = 0;                     vd[0] = true;
  jn[1] = i;                     vd[1] = true;
  jn[2] = (c > 0)  ? i - 1  : i; vd[2] = (c > 0);
  jn[3] = (c < 63) ? i + 1  : i; vd[3] = (c < 63);
  jn[4] = (r > 0)  ? i - 64 : i; vd[4] = (r > 0);
  jn[5] = (r < 63) ? i + 64 : i; vd[5] = (r < 63);

  const uint4 qv = *(const uint4*)(QKV + (base + i) * 1536 + lane * 8);
  float qf[8] = { bflo(qv.x), bfhi(qv.x), bflo(qv.y), bfhi(qv.y),
                  bflo(qv.z), bfhi(qv.z), bflo(qv.w), bfhi(qv.w) };

  float sc[6];
#pragma unroll
  for (int n = 0; n < 6; ++n) {
    const uint4 kv = *(const uint4*)(QKV + (base + jn[n]) * 1536 + 512 + lane * 8);
    float p = qf[0]*bflo(kv.x) + qf[1]*bfhi(kv.x)
            + qf[2]*bflo(kv.y) + qf[3]*bfhi(kv.y)
            + qf[4]*bflo(kv.z) + qf[5]*bfhi(kv.z)
            + qf[6]*bflo(kv.w) + qf[7]*bfhi(kv.w);
    p += __shfl_xor(p, 1);   // reduce across the 8 lanes of this head's group
    p += __shfl_xor(p, 2);
    p += __shfl_xor(p, 4);
    sc[n] = p * 0.125f;
  }
  float mx = -1e30f;
#pragma unroll
  for (int n = 0; n < 6; ++n) if (vd[n]) mx = fmaxf(mx, sc[n]);
  float pw[6], den = 0.f;
#pragma unroll
  for (int n = 0; n < 6; ++n) {
    pw[n] = vd[n] ? __expf(sc[n] - mx) : 0.f;
    den += pw[n];
  }
  const float inv = 1.f / den;

  float oa[8] = {};
#pragma unroll
  for (int n = 0; n < 6; ++n) {
    const uint4 vv = *(const uint4*)(QKV + (base + jn[n]) * 1536 + 1024 + lane * 8);
    const float w = pw[n];
    oa[0] += w * bflo(vv.x); oa[1] += w * bfhi(vv.x);
    oa[2] += w * bflo(vv.y); oa[3] += w * bfhi(vv.y);
    oa[4] += w * bflo(vv.z); oa[5] += w * bfhi(vv.z);
    oa[6] += w * bflo(vv.w); oa[7] += w * bfhi(vv.w);
  }
  uint4 ov;
  ov.x = (u32)f2bf(oa[0] * inv) | ((u32)f2bf(oa[1] * inv) << 16);
  ov.y = (u32)f2bf(oa[2] * inv) | ((u32)f2bf(oa[3] * inv) << 16);
  ov.z = (u32)f2bf(oa[4] * inv) | ((u32)f2bf(oa[5] * inv) << 16);
  ov.w = (u32)f2bf(oa[6] * inv) | ((u32)f2bf(oa[7] * inv) << 16);
  *(uint4*)(O + (base + i) * 512 + lane * 8) = ov;
}

// -------------------------------------------------------------- launch ----
extern "C" void kernel_launch(void* const* d_in, const int* in_sizes, int n_in,
                              void* d_out, int out_size, void* d_ws, size_t ws_size,
                              hipStream_t stream) {
  (void)in_sizes; (void)n_in; (void)out_size; (void)ws_size;
  const float* x  = (const float*)d_in[0];
  const float* wq = (const float*)d_in[1];
  const float* wk = (const float*)d_in[2];
  const float* wv = (const float*)d_in[3];
  const float* wo = (const float*)d_in[4];
  float* out = (float*)d_out;

  char* ws = (char*)d_ws;
  u16* Xp   = (u16*)ws;  ws += (size_t)M_PAD * 512 * 2;   //  8,519,680 B
  u16* Wqkv = (u16*)ws;  ws += (size_t)1536 * 512 * 2;    //  1,572,864 B
  u16* Wob  = (u16*)ws;  ws += (size_t)512 * 512 * 2;     //    524,288 B
  u16* QKV  = (u16*)ws;  ws += (size_t)M_PAD * 1536 * 2;  // 25,559,040 B
  u16* ATT  = (u16*)ws;                                   //  8,519,680 B

  prep<<<(NCH_X + NCH_WQ + NCH_WO) / 256, 256, 0, stream>>>(
      x, wq, wk, wv, wo, Xp, Wqkv, Wob);

  dim3 g1(M_PAD / 128, 1536 / 128);
  gemm_bt<1536, false><<<g1, 256, 0, stream>>>(Xp, Wqkv, QKV, nullptr);

  attn<<<16 + 2048, 256, 0, stream>>>(QKV, ATT);

  dim3 g2(M_PAD / 128, 512 / 128);
  gemm_bt<512, true><<<g2, 256, 0, stream>>>(ATT, Wob, nullptr, out);
}

// Round 2
// 71.634 us; speedup vs baseline: 2.3061x; 2.3061x over previous
//
#include <hip/hip_runtime.h>

#define DI __device__ __forceinline__

typedef __bf16 bf16x8 __attribute__((ext_vector_type(8)));
typedef float  f32x4  __attribute__((ext_vector_type(4)));
typedef unsigned short u16;
typedef unsigned int   u32;

constexpr int BATCH  = 2;
constexpr int NNODE  = 4097;          // 64*64 grid + 1 global token
constexpr int M_REAL = BATCH * NNODE; // 8194
constexpr int M_PAD  = 8320;          // 65 * 128
constexpr int KDIM   = 512;

// dense global-token row: split-K softmax partials
constexpr int JC     = 256;                        // keys per chunk
constexpr int NCHUNK = (NNODE + JC - 1) / JC;      // 17
constexpr int NDB    = BATCH * 8 * NCHUNK;         // 272 dense phase-A blocks

DI float bf2f(u16 u)  { return __uint_as_float(((u32)u) << 16); }
DI float bflo(u32 v)  { return __uint_as_float(v << 16); }
DI float bfhi(u32 v)  { return __uint_as_float(v & 0xffff0000u); }
DI u16   f2bf(float f) {
  u32 u = __float_as_uint(f);
  u32 r = (u + 0x7fffu + ((u >> 16) & 1u)) >> 16;   // RNE
  return (u16)r;
}

DI void gload_lds16(const void* g, void* l) {
  __builtin_amdgcn_global_load_lds(
      (const __attribute__((address_space(1))) u32*)g,
      (__attribute__((address_space(3))) u32*)l, 16, 0, 0);
}

// ---------------------------------------------------------------- prep ----
constexpr int NCH_X  = M_PAD * KDIM / 8;   // 532480
constexpr int NCH_WQ = 1536 * KDIM / 8;    // 98304
constexpr int NCH_WO = 512 * KDIM / 8;     // 32768

__global__ __launch_bounds__(256) void prep(
    const float* __restrict__ x,  const float* __restrict__ wq,
    const float* __restrict__ wk, const float* __restrict__ wv,
    const float* __restrict__ wo,
    u16* __restrict__ Xp, u16* __restrict__ Wqkv, u16* __restrict__ Wob) {
  int idx = blockIdx.x * 256 + threadIdx.x;
  const float* src = nullptr;
  u16* dst = nullptr;
  bool zero = false;
  if (idx < NCH_X) {
    int row = idx >> 6;
    dst = Xp + (size_t)idx * 8;
    if (row < M_REAL) src = x + (size_t)idx * 8; else zero = true;
  } else if (idx < NCH_X + NCH_WQ) {
    int t = idx - NCH_X;
    int row = t >> 6;
    dst = Wqkv + (size_t)t * 8;
    const float* W = row < 512 ? wq : (row < 1024 ? wk : wv);
    src = W + ((size_t)(row & 511) << 9) + ((t & 63) * 8);
  } else if (idx < NCH_X + NCH_WQ + NCH_WO) {
    int t = idx - NCH_X - NCH_WQ;
    dst = Wob + (size_t)t * 8;
    src = wo + (size_t)t * 8;
  } else {
    return;
  }
  u32 o[4];
  if (zero) {
    o[0] = o[1] = o[2] = o[3] = 0u;
  } else {
    float4 f0 = ((const float4*)src)[0];
    float4 f1 = ((const float4*)src)[1];
    o[0] = (u32)f2bf(f0.x) | ((u32)f2bf(f0.y) << 16);
    o[1] = (u32)f2bf(f0.z) | ((u32)f2bf(f0.w) << 16);
    o[2] = (u32)f2bf(f1.x) | ((u32)f2bf(f1.y) << 16);
    o[3] = (u32)f2bf(f1.z) | ((u32)f2bf(f1.w) << 16);
  }
  uint4 v; v.x = o[0]; v.y = o[1]; v.z = o[2]; v.w = o[3];
  *(uint4*)dst = v;
}

// ---------------------------------------------------------------- GEMM ----
template <int N, bool OUT_F32>
__global__ __launch_bounds__(256) void gemm_bt(
    const u16* __restrict__ A, const u16* __restrict__ B,
    u16* __restrict__ Cb, float* __restrict__ Cf) {
  __shared__ __align__(16) u16 As[128 * 64];
  __shared__ __align__(16) u16 Bs[128 * 64];
  const int tid  = threadIdx.x;
  const int lane = tid & 63;
  const int wm = ((tid >> 6) >> 1) * 64;
  const int wn = ((tid >> 6) & 1) * 64;
  const int m0 = blockIdx.x * 128;
  const int n0 = blockIdx.y * 128;

  f32x4 acc[4][4] = {};

  const int rstg = tid >> 3;
  const int cstg = (tid & 7) * 8;
  const u16* Ag = A + (size_t)(m0 + rstg) * KDIM + cstg;
  const u16* Bg = B + (size_t)(n0 + rstg) * KDIM + cstg;
  char* AsB = (char*)As + tid * 16;
  char* BsB = (char*)Bs + tid * 16;

  for (int kt = 0; kt < KDIM; kt += 64) {
#pragma unroll
    for (int inst = 0; inst < 4; ++inst) {
      gload_lds16(Ag + (size_t)inst * 32 * KDIM + kt, AsB + inst * 4096);
      gload_lds16(Bg + (size_t)inst * 32 * KDIM + kt, BsB + inst * 4096);
    }
    __syncthreads();
#pragma unroll
    for (int kc = 0; kc < 2; ++kc) {
      const int ko = kc * 32 + (lane >> 4) * 8;
      bf16x8 af[4], bfr[4];
#pragma unroll
      for (int mi = 0; mi < 4; ++mi)
        af[mi] = *(const bf16x8*)&As[(wm + mi * 16 + (lane & 15)) * 64 + ko];
#pragma unroll
      for (int ni = 0; ni < 4; ++ni)
        bfr[ni] = *(const bf16x8*)&Bs[(wn + ni * 16 + (lane & 15)) * 64 + ko];
#pragma unroll
      for (int mi = 0; mi < 4; ++mi)
#pragma unroll
        for (int ni = 0; ni < 4; ++ni)
          acc[mi][ni] = __builtin_amdgcn_mfma_f32_16x16x32_bf16(
              af[mi], bfr[ni], acc[mi][ni], 0, 0, 0);
    }
    __syncthreads();
  }

  const int cr = (lane >> 4) * 4;
  const int cc = lane & 15;
#pragma unroll
  for (int mi = 0; mi < 4; ++mi) {
#pragma unroll
    for (int j = 0; j < 4; ++j) {
      const int row = m0 + wm + mi * 16 + cr + j;
      if (OUT_F32 && row >= M_REAL) continue;
#pragma unroll
      for (int ni = 0; ni < 4; ++ni) {
        const int col = n0 + wn + ni * 16 + cc;
        if constexpr (OUT_F32)
          Cf[(size_t)row * N + col] = acc[mi][ni][j];
        else
          Cb[(size_t)row * N + col] = f2bf(acc[mi][ni][j]);
      }
    }
  }
}

// ------------------------------------------------------------ attention ----
// QKV: [M_PAD][1536] bf16  (q 0..511 | k 512..1023 | v 1024..1535)
// O:   [M_PAD][512]  bf16
// blocks [0,NDB): dense-row phase A (split-K partials -> Part)
// blocks [NDB,..): sparse rows, one wave per (b, grid node), <=6 keys.
__global__ __launch_bounds__(256) void attn(const u16* __restrict__ QKV,
                                            u16* __restrict__ O,
                                            float* __restrict__ Part) {
  const int tid = threadIdx.x;
  if (blockIdx.x < NDB) {
    // ---- dense global-token row, chunk partials ----
    __shared__ float qs[64];
    __shared__ float ev[JC];
    __shared__ float red[256];
    const int db = blockIdx.x;
    const int b  = db / (8 * NCHUNK);
    const int rm = db % (8 * NCHUNK);
    const int h  = rm / NCHUNK;
    const int ch = rm % NCHUNK;
    const int j0 = ch * JC;
    const size_t base = (size_t)b * NNODE;

    if (tid < 64) qs[tid] = bf2f(QKV[base * 1536 + h * 64 + tid]);
    __syncthreads();

    const int j = j0 + tid;
    float s = -3e38f;
    if (j < NNODE) {
      const uint4* kp4 = (const uint4*)(QKV + (base + j) * 1536 + 512 + h * 64);
      float a = 0.f;
#pragma unroll
      for (int q8 = 0; q8 < 8; ++q8) {
        uint4 kv = kp4[q8];
        int d = q8 * 8;
        a += qs[d+0]*bflo(kv.x) + qs[d+1]*bfhi(kv.x)
           + qs[d+2]*bflo(kv.y) + qs[d+3]*bfhi(kv.y)
           + qs[d+4]*bflo(kv.z) + qs[d+5]*bfhi(kv.z)
           + qs[d+6]*bflo(kv.w) + qs[d+7]*bfhi(kv.w);
      }
      s = a * 0.125f;
    }
    red[tid] = s;
    __syncthreads();
    for (int st = 128; st > 0; st >>= 1) {
      if (tid < st) red[tid] = fmaxf(red[tid], red[tid + st]);
      __syncthreads();
    }
    const float mx = red[0];
    __syncthreads();
    const float e = (j < NNODE) ? __expf(s - mx) : 0.f;
    ev[tid] = e;
    red[tid] = e;
    __syncthreads();
    for (int st = 128; st > 0; st >>= 1) {
      if (tid < st) red[tid] += red[tid + st];
      __syncthreads();
    }
    const float ssum = red[0];
    __syncthreads();

    // PV partial: wave w covers 64 local keys; lane = j_sub*8 + d_grp
    const int w = tid >> 6, lane = tid & 63;
    const int js = lane >> 3, dg = lane & 7;
    float oa[8] = {};
#pragma unroll
    for (int jj = 0; jj < 8; ++jj) {
      const int li = w * 64 + jj * 8 + js;
      const int jv = j0 + li;
      if (jv < NNODE) {
        const float we = ev[li];
        const uint4 vv = *(const uint4*)(QKV + (base + jv) * 1536 + 1024 + h * 64 + dg * 8);
        oa[0] += we * bflo(vv.x); oa[1] += we * bfhi(vv.x);
        oa[2] += we * bflo(vv.y); oa[3] += we * bfhi(vv.y);
        oa[4] += we * bflo(vv.z); oa[5] += we * bfhi(vv.z);
        oa[6] += we * bflo(vv.w); oa[7] += we * bfhi(vv.w);
      }
    }
#pragma unroll
    for (int m = 8; m <= 32; m <<= 1)
#pragma unroll
      for (int t = 0; t < 8; ++t) oa[t] += __shfl_xor(oa[t], m);
    __syncthreads();
    if (lane < 8) {
#pragma unroll
      for (int t = 0; t < 8; ++t) red[w * 64 + lane * 8 + t] = oa[t];
    }
    __syncthreads();
    float* P = Part + ((size_t)((b * 8 + h) * NCHUNK + ch)) * 66;
    if (tid == 0) { P[0] = mx; P[1] = ssum; }
    if (tid < 64)
      P[2 + tid] = red[tid] + red[64 + tid] + red[128 + tid] + red[192 + tid];
    return;
  }

  // ---- sparse rows: one wave per (b, node) ----
  const int wid  = (blockIdx.x - NDB) * 4 + (tid >> 6);  // 0..8191
  const int lane = tid & 63;
  const int b = wid >> 12;
  const int g = wid & 4095;
  const int i = g + 1;
  const int r = g >> 6, c = g & 63;
  const size_t base = (size_t)b * NNODE;

  int  jn[6];
  bool vd[6];
  jn[0] = 0;                     vd[0] = true;
  jn[1] = i;                     vd[1] = true;
  jn[2] = (c > 0)  ? i - 1  : i; vd[2] = (c > 0);
  jn[3] = (c < 63) ? i + 1  : i; vd[3] = (c < 63);
  jn[4] = (r > 0)  ? i - 64 : i; vd[4] = (r > 0);
  jn[5] = (r < 63) ? i + 64 : i; vd[5] = (r < 63);

  const uint4 qv = *(const uint4*)(QKV + (base + i) * 1536 + lane * 8);
  float qf[8] = { bflo(qv.x), bfhi(qv.x), bflo(qv.y), bfhi(qv.y),
                  bflo(qv.z), bfhi(qv.z), bflo(qv.w), bfhi(qv.w) };

  float sc[6];
#pragma unroll
  for (int n = 0; n < 6; ++n) {
    const uint4 kv = *(const uint4*)(QKV + (base + jn[n]) * 1536 + 512 + lane * 8);
    float p = qf[0]*bflo(kv.x) + qf[1]*bfhi(kv.x)
            + qf[2]*bflo(kv.y) + qf[3]*bfhi(kv.y)
            + qf[4]*bflo(kv.z) + qf[5]*bfhi(kv.z)
            + qf[6]*bflo(kv.w) + qf[7]*bfhi(kv.w);
    p += __shfl_xor(p, 1);
    p += __shfl_xor(p, 2);
    p += __shfl_xor(p, 4);
    sc[n] = p * 0.125f;
  }
  float mx = -1e30f;
#pragma unroll
  for (int n = 0; n < 6; ++n) if (vd[n]) mx = fmaxf(mx, sc[n]);
  float pw[6], den = 0.f;
#pragma unroll
  for (int n = 0; n < 6; ++n) {
    pw[n] = vd[n] ? __expf(sc[n] - mx) : 0.f;
    den += pw[n];
  }
  const float inv = 1.f / den;

  float oa[8] = {};
#pragma unroll
  for (int n = 0; n < 6; ++n) {
    const uint4 vv = *(const uint4*)(QKV + (base + jn[n]) * 1536 + 1024 + lane * 8);
    const float w = pw[n];
    oa[0] += w * bflo(vv.x); oa[1] += w * bfhi(vv.x);
    oa[2] += w * bflo(vv.y); oa[3] += w * bfhi(vv.y);
    oa[4] += w * bflo(vv.z); oa[5] += w * bfhi(vv.z);
    oa[6] += w * bflo(vv.w); oa[7] += w * bfhi(vv.w);
  }
  uint4 ov;
  ov.x = (u32)f2bf(oa[0] * inv) | ((u32)f2bf(oa[1] * inv) << 16);
  ov.y = (u32)f2bf(oa[2] * inv) | ((u32)f2bf(oa[3] * inv) << 16);
  ov.z = (u32)f2bf(oa[4] * inv) | ((u32)f2bf(oa[5] * inv) << 16);
  ov.w = (u32)f2bf(oa[6] * inv) | ((u32)f2bf(oa[7] * inv) << 16);
  *(uint4*)(O + (base + i) * 512 + lane * 8) = ov;
}

// phase B: merge the NCHUNK partials per (b,h), write O row 0.
__global__ __launch_bounds__(64) void attn_fin(const float* __restrict__ Part,
                                               u16* __restrict__ O) {
  const int b = blockIdx.x >> 3, h = blockIdx.x & 7;
  const int d = threadIdx.x;
  const float* P = Part + ((size_t)(b * 8 + h) * NCHUNK) * 66;
  float m = -3e38f;
  for (int c = 0; c < NCHUNK; ++c) m = fmaxf(m, P[c * 66]);
  float s = 0.f, o = 0.f;
  for (int c = 0; c < NCHUNK; ++c) {
    const float ex = __expf(P[c * 66] - m);
    s += P[c * 66 + 1] * ex;
    o += P[c * 66 + 2 + d] * ex;
  }
  O[(size_t)b * NNODE * 512 + h * 64 + d] = f2bf(o / s);
}

// -------------------------------------------------------------- launch ----
extern "C" void kernel_launch(void* const* d_in, const int* in_sizes, int n_in,
                              void* d_out, int out_size, void* d_ws, size_t ws_size,
                              hipStream_t stream) {
  (void)in_sizes; (void)n_in; (void)out_size; (void)ws_size;
  const float* x  = (const float*)d_in[0];
  const float* wq = (const float*)d_in[1];
  const float* wk = (const float*)d_in[2];
  const float* wv = (const float*)d_in[3];
  const float* wo = (const float*)d_in[4];
  float* out = (float*)d_out;

  char* ws = (char*)d_ws;
  u16* Xp   = (u16*)ws;  ws += (size_t)M_PAD * 512 * 2;   //  8,519,680 B
  u16* Wqkv = (u16*)ws;  ws += (size_t)1536 * 512 * 2;    //  1,572,864 B
  u16* Wob  = (u16*)ws;  ws += (size_t)512 * 512 * 2;     //    524,288 B
  u16* QKV  = (u16*)ws;  ws += (size_t)M_PAD * 1536 * 2;  // 25,559,040 B
  u16* ATT  = (u16*)ws;                                   //  8,519,680 B
  // dense partials reuse the Xp region (dead after gemm1): 272*66*4 = 72 KB
  float* Part = (float*)Xp;

  prep<<<(NCH_X + NCH_WQ + NCH_WO) / 256, 256, 0, stream>>>(
      x, wq, wk, wv, wo, Xp, Wqkv, Wob);

  dim3 g1(M_PAD / 128, 1536 / 128);
  gemm_bt<1536, false><<<g1, 256, 0, stream>>>(Xp, Wqkv, QKV, nullptr);

  attn<<<NDB + 2048, 256, 0, stream>>>(QKV, ATT, Part);
  attn_fin<<<16, 64, 0, stream>>>(Part, ATT);

  dim3 g2(M_PAD / 128, 512 / 128);
  gemm_bt<512, true><<<g2, 256, 0, stream>>>(ATT, Wob, nullptr, out);
}

// Round 4
// 66.181 us; speedup vs baseline: 2.4961x; 1.0824x over previous
//
#include <hip/hip_runtime.h>

#define DI __device__ __forceinline__

typedef __bf16 bf16x8 __attribute__((ext_vector_type(8)));
typedef float  f32x4  __attribute__((ext_vector_type(4)));
typedef unsigned short u16;
typedef unsigned int   u32;

constexpr int BATCH  = 2;
constexpr int NNODE  = 4097;          // 64*64 grid + 1 global token
constexpr int M_REAL = BATCH * NNODE; // 8194
constexpr int M_PAD  = 8448;          // 33 * 256
constexpr int KDIM   = 512;

// dense global-token row: split-K softmax partials
constexpr int JC     = 256;                        // keys per chunk
constexpr int NCHUNK = (NNODE + JC - 1) / JC;      // 17
constexpr int NDB    = BATCH * 8 * NCHUNK;         // 272 dense phase-A blocks

DI float bf2f(u16 u)  { return __uint_as_float(((u32)u) << 16); }
DI float bflo(u32 v)  { return __uint_as_float(v << 16); }
DI float bfhi(u32 v)  { return __uint_as_float(v & 0xffff0000u); }
DI u16   f2bf(float f) {
  u32 u = __float_as_uint(f);
  u32 r = (u + 0x7fffu + ((u >> 16) & 1u)) >> 16;   // RNE
  return (u16)r;
}

DI void gload_lds16(const void* g, void* l) {
  __builtin_amdgcn_global_load_lds(
      (const __attribute__((address_space(1))) u32*)g,
      (__attribute__((address_space(3))) u32*)l, 16, 0, 0);
}

// ---------------------------------------------------------------- prep ----
constexpr int NCH_X  = M_PAD * KDIM / 8;   // 540672
constexpr int NCH_WQ = 1536 * KDIM / 8;    // 98304
constexpr int NCH_WO = 512 * KDIM / 8;     // 32768

__global__ __launch_bounds__(256) void prep(
    const float* __restrict__ x,  const float* __restrict__ wq,
    const float* __restrict__ wk, const float* __restrict__ wv,
    const float* __restrict__ wo,
    u16* __restrict__ Xp, u16* __restrict__ Wqkv, u16* __restrict__ Wob) {
  int idx = blockIdx.x * 256 + threadIdx.x;
  const float* src = nullptr;
  u16* dst = nullptr;
  bool zero = false;
  if (idx < NCH_X) {
    int row = idx >> 6;
    dst = Xp + (size_t)idx * 8;
    if (row < M_REAL) src = x + (size_t)idx * 8; else zero = true;
  } else if (idx < NCH_X + NCH_WQ) {
    int t = idx - NCH_X;
    int row = t >> 6;
    dst = Wqkv + (size_t)t * 8;
    const float* W = row < 512 ? wq : (row < 1024 ? wk : wv);
    src = W + ((size_t)(row & 511) << 9) + ((t & 63) * 8);
  } else if (idx < NCH_X + NCH_WQ + NCH_WO) {
    int t = idx - NCH_X - NCH_WQ;
    dst = Wob + (size_t)t * 8;
    src = wo + (size_t)t * 8;
  } else {
    return;
  }
  u32 o[4];
  if (zero) {
    o[0] = o[1] = o[2] = o[3] = 0u;
  } else {
    float4 f0 = ((const float4*)src)[0];
    float4 f1 = ((const float4*)src)[1];
    o[0] = (u32)f2bf(f0.x) | ((u32)f2bf(f0.y) << 16);
    o[1] = (u32)f2bf(f0.z) | ((u32)f2bf(f0.w) << 16);
    o[2] = (u32)f2bf(f1.x) | ((u32)f2bf(f1.y) << 16);
    o[3] = (u32)f2bf(f1.z) | ((u32)f2bf(f1.w) << 16);
  }
  uint4 v; v.x = o[0]; v.y = o[1]; v.z = o[2]; v.w = o[3];
  *(uint4*)dst = v;
}

// ------------------------------------------------- 256x256 dbuf GEMM ------
// C[m,n] = sum_k A[m,k]*B[n,k]; A [M_PAD][512], B [1536][512] bf16, C bf16.
// 8 waves (2M x 4N), per-wave 128x64 out. BK=64, LDS 128KB double-buffered.
// Swizzle: LDS[row][g] holds global granule g ^ (row&7) (granule = 8 elems).
// Sync per tile: stage(t+1) -> vmcnt(8) -> s_barrier -> reads+MFMA -> barrier.
__global__ __launch_bounds__(512, 2) void gemm256(
    const u16* __restrict__ A, const u16* __restrict__ B,
    u16* __restrict__ C) {
  __shared__ __align__(16) u16 SM[65536];  // A: bytes [0,64K) 2 bufs; B: [64K,128K)
  const int tid  = threadIdx.x;
  const int lane = tid & 63;
  const int wid  = tid >> 6;
  const int wm   = wid >> 2;   // 0..1
  const int wn   = wid & 3;    // 0..3
  const int m0 = blockIdx.x * 256;
  const int n0 = blockIdx.y * 256;

  const int l15 = lane & 15, l7 = lane & 7, lg = lane >> 4;

  // staging: thread covers (row = tid>>3, lds-granule = tid&7);
  // pre-swizzled global granule = (tid&7) ^ (row&7)
  const int srow = tid >> 3;
  const int scol = ((tid & 7) ^ (srow & 7)) << 3;
  const u16* Ag = A + (size_t)(m0 + srow) * KDIM + scol;
  const u16* Bg = B + (size_t)(n0 + srow) * KDIM + scol;

  // fragment k-offsets (elements), swizzled by row&7 (= l7 for 16-aligned rows)
  const int kx0 = ((lg * 8)        ^ (l7 << 3));
  const int kx1 = (((4 | lg) * 8)  ^ (l7 << 3));
  // fragment row bases (elements into SM)
  const int aBase = wm * 8192 + l15 * 64;
  const int bBase = 32768 + (wn >> 1) * 8192 + ((wn & 1) * 64 + l15) * 64;

  f32x4 acc[8][4] = {};

  constexpr int NT = KDIM / 64;  // 8 K-tiles

  auto stage = [&](int t, int buf) {
    const int ab = buf * 32768;  // bytes per A/B double-buffer slot
    const u16* ga = Ag + t * 64;
    const u16* gb = Bg + t * 64;
#pragma unroll
    for (int h = 0; h < 4; ++h) {
      gload_lds16(ga + (size_t)h * 64 * KDIM, (char*)SM + ab + h * 8192 + tid * 16);
      gload_lds16(gb + (size_t)h * 64 * KDIM, (char*)SM + 65536 + ab + h * 8192 + tid * 16);
    }
  };

  stage(0, 0);

  for (int t = 0; t < NT; ++t) {
    const int buf = t & 1;
    if (t + 1 < NT) {
      stage(t + 1, buf ^ 1);
      asm volatile("s_waitcnt vmcnt(8)" ::: "memory");  // drain tile t, keep t+1
    } else {
      asm volatile("s_waitcnt vmcnt(0)" ::: "memory");
    }
    asm volatile("s_barrier" ::: "memory");  // all waves: tile t resident in LDS

    const int aB = aBase + buf * 16384;   // elements
    const int bB = bBase + buf * 16384;
#pragma unroll
    for (int p = 0; p < 4; ++p) {         // quadrants: (qm, qn)
      const int qm = p & 1, qn = p >> 1;
      bf16x8 af[4][2], bfr[2][2];
#pragma unroll
      for (int i = 0; i < 4; ++i) {
        const int mi = qm * 4 + i;
        af[i][0] = *(const bf16x8*)&SM[aB + mi * 1024 + kx0];
        af[i][1] = *(const bf16x8*)&SM[aB + mi * 1024 + kx1];
      }
#pragma unroll
      for (int i = 0; i < 2; ++i) {
        const int ni = qn * 2 + i;
        bfr[i][0] = *(const bf16x8*)&SM[bB + ni * 1024 + kx0];
        bfr[i][1] = *(const bf16x8*)&SM[bB + ni * 1024 + kx1];
      }
      __builtin_amdgcn_s_setprio(1);
#pragma unroll
      for (int i = 0; i < 4; ++i)
#pragma unroll
        for (int jn = 0; jn < 2; ++jn) {
          acc[qm*4+i][qn*2+jn] = __builtin_amdgcn_mfma_f32_16x16x32_bf16(
              af[i][0], bfr[jn][0], acc[qm*4+i][qn*2+jn], 0, 0, 0);
          acc[qm*4+i][qn*2+jn] = __builtin_amdgcn_mfma_f32_16x16x32_bf16(
              af[i][1], bfr[jn][1], acc[qm*4+i][qn*2+jn], 0, 0, 0);
        }
      __builtin_amdgcn_s_setprio(0);
    }
    asm volatile("s_barrier" ::: "memory");  // reads done before buf reuse
  }

  const int cr = lg * 4, cc = l15;
#pragma unroll
  for (int mi = 0; mi < 8; ++mi)
#pragma unroll
    for (int j = 0; j < 4; ++j) {
      const int row = m0 + wm * 128 + mi * 16 + cr + j;
#pragma unroll
      for (int ni = 0; ni < 4; ++ni) {
        const int col = n0 + wn * 64 + ni * 16 + cc;
        C[(size_t)row * 1536 + col] = f2bf(acc[mi][ni][j]);
      }
    }
}

// ----------------------------------------------- 128x128 GEMM (output) ----
template <int N, bool OUT_F32>
__global__ __launch_bounds__(256) void gemm_bt(
    const u16* __restrict__ A, const u16* __restrict__ B,
    u16* __restrict__ Cb, float* __restrict__ Cf) {
  __shared__ __align__(16) u16 As[128 * 64];
  __shared__ __align__(16) u16 Bs[128 * 64];
  const int tid  = threadIdx.x;
  const int lane = tid & 63;
  const int wm = ((tid >> 6) >> 1) * 64;
  const int wn = ((tid >> 6) & 1) * 64;
  const int m0 = blockIdx.x * 128;
  const int n0 = blockIdx.y * 128;

  f32x4 acc[4][4] = {};

  const int rstg = tid >> 3;
  const int cstg = (tid & 7) * 8;
  const u16* Ag = A + (size_t)(m0 + rstg) * KDIM + cstg;
  const u16* Bg = B + (size_t)(n0 + rstg) * KDIM + cstg;
  char* AsB = (char*)As + tid * 16;
  char* BsB = (char*)Bs + tid * 16;

  for (int kt = 0; kt < KDIM; kt += 64) {
#pragma unroll
    for (int inst = 0; inst < 4; ++inst) {
      gload_lds16(Ag + (size_t)inst * 32 * KDIM + kt, AsB + inst * 4096);
      gload_lds16(Bg + (size_t)inst * 32 * KDIM + kt, BsB + inst * 4096);
    }
    __syncthreads();
#pragma unroll
    for (int kc = 0; kc < 2; ++kc) {
      const int ko = kc * 32 + (lane >> 4) * 8;
      bf16x8 af[4], bfr[4];
#pragma unroll
      for (int mi = 0; mi < 4; ++mi)
        af[mi] = *(const bf16x8*)&As[(wm + mi * 16 + (lane & 15)) * 64 + ko];
#pragma unroll
      for (int ni = 0; ni < 4; ++ni)
        bfr[ni] = *(const bf16x8*)&Bs[(wn + ni * 16 + (lane & 15)) * 64 + ko];
#pragma unroll
      for (int mi = 0; mi < 4; ++mi)
#pragma unroll
        for (int ni = 0; ni < 4; ++ni)
          acc[mi][ni] = __builtin_amdgcn_mfma_f32_16x16x32_bf16(
              af[mi], bfr[ni], acc[mi][ni], 0, 0, 0);
    }
    __syncthreads();
  }

  const int cr = (lane >> 4) * 4;
  const int cc = lane & 15;
#pragma unroll
  for (int mi = 0; mi < 4; ++mi) {
#pragma unroll
    for (int j = 0; j < 4; ++j) {
      const int row = m0 + wm + mi * 16 + cr + j;
      if (OUT_F32 && row >= M_REAL) continue;
#pragma unroll
      for (int ni = 0; ni < 4; ++ni) {
        const int col = n0 + wn + ni * 16 + cc;
        if constexpr (OUT_F32)
          Cf[(size_t)row * N + col] = acc[mi][ni][j];
        else
          Cb[(size_t)row * N + col] = f2bf(acc[mi][ni][j]);
      }
    }
  }
}

// ------------------------------------------------------------ attention ----
__global__ __launch_bounds__(256) void attn(const u16* __restrict__ QKV,
                                            u16* __restrict__ O,
                                            float* __restrict__ Part) {
  const int tid = threadIdx.x;
  if (blockIdx.x < NDB) {
    // ---- dense global-token row, chunk partials ----
    __shared__ float qs[64];
    __shared__ float ev[JC];
    __shared__ float red[256];
    const int db = blockIdx.x;
    const int b  = db / (8 * NCHUNK);
    const int rm = db % (8 * NCHUNK);
    const int h  = rm / NCHUNK;
    const int ch = rm % NCHUNK;
    const int j0 = ch * JC;
    const size_t base = (size_t)b * NNODE;

    if (tid < 64) qs[tid] = bf2f(QKV[base * 1536 + h * 64 + tid]);
    __syncthreads();

    const int j = j0 + tid;
    float s = -3e38f;
    if (j < NNODE) {
      const uint4* kp4 = (const uint4*)(QKV + (base + j) * 1536 + 512 + h * 64);
      float a = 0.f;
#pragma unroll
      for (int q8 = 0; q8 < 8; ++q8) {
        uint4 kv = kp4[q8];
        int d = q8 * 8;
        a += qs[d+0]*bflo(kv.x) + qs[d+1]*bfhi(kv.x)
           + qs[d+2]*bflo(kv.y) + qs[d+3]*bfhi(kv.y)
           + qs[d+4]*bflo(kv.z) + qs[d+5]*bfhi(kv.z)
           + qs[d+6]*bflo(kv.w) + qs[d+7]*bfhi(kv.w);
      }
      s = a * 0.125f;
    }
    red[tid] = s;
    __syncthreads();
    for (int st = 128; st > 0; st >>= 1) {
      if (tid < st) red[tid] = fmaxf(red[tid], red[tid + st]);
      __syncthreads();
    }
    const float mx = red[0];
    __syncthreads();
    const float e = (j < NNODE) ? __expf(s - mx) : 0.f;
    ev[tid] = e;
    red[tid] = e;
    __syncthreads();
    for (int st = 128; st > 0; st >>= 1) {
      if (tid < st) red[tid] += red[tid + st];
      __syncthreads();
    }
    const float ssum = red[0];
    __syncthreads();

    const int w = tid >> 6, lane = tid & 63;
    const int js = lane >> 3, dg = lane & 7;
    float oa[8] = {};
#pragma unroll
    for (int jj = 0; jj < 8; ++jj) {
      const int li = w * 64 + jj * 8 + js;
      const int jv = j0 + li;
      if (jv < NNODE) {
        const float we = ev[li];
        const uint4 vv = *(const uint4*)(QKV + (base + jv) * 1536 + 1024 + h * 64 + dg * 8);
        oa[0] += we * bflo(vv.x); oa[1] += we * bfhi(vv.x);
        oa[2] += we * bflo(vv.y); oa[3] += we * bfhi(vv.y);
        oa[4] += we * bflo(vv.z); oa[5] += we * bfhi(vv.z);
        oa[6] += we * bflo(vv.w); oa[7] += we * bfhi(vv.w);
      }
    }
#pragma unroll
    for (int m = 8; m <= 32; m <<= 1)
#pragma unroll
      for (int t = 0; t < 8; ++t) oa[t] += __shfl_xor(oa[t], m);
    __syncthreads();
    if (lane < 8) {
#pragma unroll
      for (int t = 0; t < 8; ++t) red[w * 64 + lane * 8 + t] = oa[t];
    }
    __syncthreads();
    float* P = Part + ((size_t)((b * 8 + h) * NCHUNK + ch)) * 66;
    if (tid == 0) { P[0] = mx; P[1] = ssum; }
    if (tid < 64)
      P[2 + tid] = red[tid] + red[64 + tid] + red[128 + tid] + red[192 + tid];
    return;
  }

  // ---- sparse rows: one wave per (b, node); XCD-chunked block swizzle ----
  const int obid = blockIdx.x - NDB;                    // 0..2047
  const int sb   = ((obid & 7) << 8) | (obid >> 3);     // bijective (2048 % 8 == 0)
  const int wid  = sb * 4 + (tid >> 6);                 // 0..8191
  const int lane = tid & 63;
  const int b = wid >> 12;
  const int g = wid & 4095;
  const int i = g + 1;
  const int r = g >> 6, c = g & 63;
  const size_t base = (size_t)b * NNODE;

  int  jn[6];
  bool vd[6];
  jn[0] = 0;                     vd[0] = true;
  jn[1] = i;                     vd[1] = true;
  jn[2] = (c > 0)  ? i - 1  : i; vd[2] = (c > 0);
  jn[3] = (c < 63) ? i + 1  : i; vd[3] = (c < 63);
  jn[4] = (r > 0)  ? i - 64 : i; vd[4] = (r > 0);
  jn[5] = (r < 63) ? i + 64 : i; vd[5] = (r < 63);

  const uint4 qv = *(const uint4*)(QKV + (base + i) * 1536 + lane * 8);
  float qf[8] = { bflo(qv.x), bfhi(qv.x), bflo(qv.y), bfhi(qv.y),
                  bflo(qv.z), bfhi(qv.z), bflo(qv.w), bfhi(qv.w) };

  float sc[6];
#pragma unroll
  for (int n = 0; n < 6; ++n) {
    const uint4 kv = *(const uint4*)(QKV + (base + jn[n]) * 1536 + 512 + lane * 8);
    float p = qf[0]*bflo(kv.x) + qf[1]*bfhi(kv.x)
            + qf[2]*bflo(kv.y) + qf[3]*bfhi(kv.y)
            + qf[4]*bflo(kv.z) + qf[5]*bfhi(kv.z)
            + qf[6]*bflo(kv.w) + qf[7]*bfhi(kv.w);
    p += __shfl_xor(p, 1);
    p += __shfl_xor(p, 2);
    p += __shfl_xor(p, 4);
    sc[n] = p * 0.125f;
  }
  float mx = -1e30f;
#pragma unroll
  for (int n = 0; n < 6; ++n) if (vd[n]) mx = fmaxf(mx, sc[n]);
  float pw[6], den = 0.f;
#pragma unroll
  for (int n = 0; n < 6; ++n) {
    pw[n] = vd[n] ? __expf(sc[n] - mx) : 0.f;
    den += pw[n];
  }
  const float inv = 1.f / den;

  float oa[8] = {};
#pragma unroll
  for (int n = 0; n < 6; ++n) {
    const uint4 vv = *(const uint4*)(QKV + (base + jn[n]) * 1536 + 1024 + lane * 8);
    const float w = pw[n];
    oa[0] += w * bflo(vv.x); oa[1] += w * bfhi(vv.x);
    oa[2] += w * bflo(vv.y); oa[3] += w * bfhi(vv.y);
    oa[4] += w * bflo(vv.z); oa[5] += w * bfhi(vv.z);
    oa[6] += w * bflo(vv.w); oa[7] += w * bfhi(vv.w);
  }
  uint4 ov;
  ov.x = (u32)f2bf(oa[0] * inv) | ((u32)f2bf(oa[1] * inv) << 16);
  ov.y = (u32)f2bf(oa[2] * inv) | ((u32)f2bf(oa[3] * inv) << 16);
  ov.z = (u32)f2bf(oa[4] * inv) | ((u32)f2bf(oa[5] * inv) << 16);
  ov.w = (u32)f2bf(oa[6] * inv) | ((u32)f2bf(oa[7] * inv) << 16);
  *(uint4*)(O + (base + i) * 512 + lane * 8) = ov;
}

// phase B: merge the NCHUNK partials per (b,h), write O row 0.
__global__ __launch_bounds__(64) void attn_fin(const float* __restrict__ Part,
                                               u16* __restrict__ O) {
  const int b = blockIdx.x >> 3, h = blockIdx.x & 7;
  const int d = threadIdx.x;
  const float* P = Part + ((size_t)(b * 8 + h) * NCHUNK) * 66;
  float m = -3e38f;
  for (int c = 0; c < NCHUNK; ++c) m = fmaxf(m, P[c * 66]);
  float s = 0.f, o = 0.f;
  for (int c = 0; c < NCHUNK; ++c) {
    const float ex = __expf(P[c * 66] - m);
    s += P[c * 66 + 1] * ex;
    o += P[c * 66 + 2 + d] * ex;
  }
  O[(size_t)b * NNODE * 512 + h * 64 + d] = f2bf(o / s);
}

// -------------------------------------------------------------- launch ----
extern "C" void kernel_launch(void* const* d_in, const int* in_sizes, int n_in,
                              void* d_out, int out_size, void* d_ws, size_t ws_size,
                              hipStream_t stream) {
  (void)in_sizes; (void)n_in; (void)out_size; (void)ws_size;
  const float* x  = (const float*)d_in[0];
  const float* wq = (const float*)d_in[1];
  const float* wk = (const float*)d_in[2];
  const float* wv = (const float*)d_in[3];
  const float* wo = (const float*)d_in[4];
  float* out = (float*)d_out;

  char* ws = (char*)d_ws;
  u16* Xp   = (u16*)ws;  ws += (size_t)M_PAD * 512 * 2;   //  8,650,752 B
  u16* Wqkv = (u16*)ws;  ws += (size_t)1536 * 512 * 2;    //  1,572,864 B
  u16* Wob  = (u16*)ws;  ws += (size_t)512 * 512 * 2;     //    524,288 B
  u16* QKV  = (u16*)ws;  ws += (size_t)M_PAD * 1536 * 2;  // 25,952,256 B
  u16* ATT  = (u16*)ws;                                   //  8,650,752 B
  float* Part = (float*)Xp;  // dead after gemm1; 272*66*4 = 72 KB

  prep<<<(NCH_X + NCH_WQ + NCH_WO) / 256, 256, 0, stream>>>(
      x, wq, wk, wv, wo, Xp, Wqkv, Wob);

  dim3 g1(M_PAD / 256, 1536 / 256);
  gemm256<<<g1, 512, 0, stream>>>(Xp, Wqkv, QKV);

  attn<<<NDB + 2048, 256, 0, stream>>>(QKV, ATT, Part);
  attn_fin<<<16, 64, 0, stream>>>(Part, ATT);

  dim3 g2(M_PAD / 128, 512 / 128);
  gemm_bt<512, true><<<g2, 256, 0, stream>>>(ATT, Wob, nullptr, out);
}

// Round 5
// 65.098 us; speedup vs baseline: 2.5377x; 1.0166x over previous
//
#include <hip/hip_runtime.h>

#define DI __device__ __forceinline__

typedef __bf16 bf16x8 __attribute__((ext_vector_type(8)));
typedef float  f32x4  __attribute__((ext_vector_type(4)));
typedef unsigned short u16;
typedef unsigned int   u32;

constexpr int BATCH  = 2;
constexpr int NNODE  = 4097;          // 64*64 grid + 1 global token
constexpr int M_REAL = BATCH * NNODE; // 8194
constexpr int M_PAD  = 8448;          // 33 * 256
constexpr int KDIM   = 512;

// dense global-token row: split-K softmax partials
constexpr int JC     = 256;                        // keys per chunk
constexpr int NCHUNK = (NNODE + JC - 1) / JC;      // 17
constexpr int NDB    = BATCH * 8 * NCHUNK;         // 272 dense phase-A blocks

DI float bf2f(u16 u)  { return __uint_as_float(((u32)u) << 16); }
DI float bflo(u32 v)  { return __uint_as_float(v << 16); }
DI float bfhi(u32 v)  { return __uint_as_float(v & 0xffff0000u); }
DI u16   f2bf(float f) {
  u32 u = __float_as_uint(f);
  u32 r = (u + 0x7fffu + ((u >> 16) & 1u)) >> 16;   // RNE
  return (u16)r;
}

DI void gload_lds16(const void* g, void* l) {
  __builtin_amdgcn_global_load_lds(
      (const __attribute__((address_space(1))) u32*)g,
      (__attribute__((address_space(3))) u32*)l, 16, 0, 0);
}

// ---------------------------------------------------------------- prep ----
constexpr int NCH_X  = M_PAD * KDIM / 8;   // 540672
constexpr int NCH_WQ = 1536 * KDIM / 8;    // 98304
constexpr int NCH_WO = 512 * KDIM / 8;     // 32768

__global__ __launch_bounds__(256) void prep(
    const float* __restrict__ x,  const float* __restrict__ wq,
    const float* __restrict__ wk, const float* __restrict__ wv,
    const float* __restrict__ wo,
    u16* __restrict__ Xp, u16* __restrict__ Wqkv, u16* __restrict__ Wob) {
  int idx = blockIdx.x * 256 + threadIdx.x;
  const float* src = nullptr;
  u16* dst = nullptr;
  bool zero = false;
  if (idx < NCH_X) {
    int row = idx >> 6;
    dst = Xp + (size_t)idx * 8;
    if (row < M_REAL) src = x + (size_t)idx * 8; else zero = true;
  } else if (idx < NCH_X + NCH_WQ) {
    int t = idx - NCH_X;
    int row = t >> 6;
    dst = Wqkv + (size_t)t * 8;
    const float* W = row < 512 ? wq : (row < 1024 ? wk : wv);
    src = W + ((size_t)(row & 511) << 9) + ((t & 63) * 8);
  } else if (idx < NCH_X + NCH_WQ + NCH_WO) {
    int t = idx - NCH_X - NCH_WQ;
    dst = Wob + (size_t)t * 8;
    src = wo + (size_t)t * 8;
  } else {
    return;
  }
  u32 o[4];
  if (zero) {
    o[0] = o[1] = o[2] = o[3] = 0u;
  } else {
    float4 f0 = ((const float4*)src)[0];
    float4 f1 = ((const float4*)src)[1];
    o[0] = (u32)f2bf(f0.x) | ((u32)f2bf(f0.y) << 16);
    o[1] = (u32)f2bf(f0.z) | ((u32)f2bf(f0.w) << 16);
    o[2] = (u32)f2bf(f1.x) | ((u32)f2bf(f1.y) << 16);
    o[3] = (u32)f2bf(f1.z) | ((u32)f2bf(f1.w) << 16);
  }
  uint4 v; v.x = o[0]; v.y = o[1]; v.z = o[2]; v.w = o[3];
  *(uint4*)dst = v;
}

// ------------------------------------------------- 256x256 dbuf GEMM ------
// C[m,n] = sum_k A[m,k]*B[n,k]; A [M_PAD][512], B [1536][512] bf16, C bf16.
// 8 waves (2M x 4N), per-wave 128x64 out. BK=64, LDS 128KB double-buffered.
// Swizzle: LDS[row][g] holds global granule g ^ (row&7) (granule = 8 elems).
// Sync per tile: stage(t+1) -> vmcnt(8) -> s_barrier -> reads+MFMA -> barrier.
// Fragment reads hoisted to the LDS floor: 24 ds_read_b128 / wave / tile.
__global__ __launch_bounds__(512, 2) void gemm256(
    const u16* __restrict__ A, const u16* __restrict__ B,
    u16* __restrict__ C) {
  __shared__ __align__(16) u16 SM[65536];  // A: bytes [0,64K) 2 bufs; B: [64K,128K)
  const int tid  = threadIdx.x;
  const int lane = tid & 63;
  const int wid  = tid >> 6;
  const int wm   = wid >> 2;   // 0..1
  const int wn   = wid & 3;    // 0..3
  const int m0 = blockIdx.x * 256;
  const int n0 = blockIdx.y * 256;

  const int l15 = lane & 15, l7 = lane & 7, lg = lane >> 4;

  // staging: thread covers (row = tid>>3, lds-granule = tid&7);
  // pre-swizzled global granule = (tid&7) ^ (row&7)
  const int srow = tid >> 3;
  const int scol = ((tid & 7) ^ (srow & 7)) << 3;
  const u16* Ag = A + (size_t)(m0 + srow) * KDIM + scol;
  const u16* Bg = B + (size_t)(n0 + srow) * KDIM + scol;

  // fragment k-offsets (elements), swizzled by row&7 (= l7 for 16-aligned rows)
  const int kx0 = ((lg * 8)        ^ (l7 << 3));
  const int kx1 = (((4 | lg) * 8)  ^ (l7 << 3));
  // fragment row bases (elements into SM)
  const int aBase = wm * 8192 + l15 * 64;
  const int bBase = 32768 + (wn >> 1) * 8192 + ((wn & 1) * 64 + l15) * 64;

  f32x4 acc[8][4] = {};

  constexpr int NT = KDIM / 64;  // 8 K-tiles

  auto stage = [&](int t, int buf) {
    const int ab = buf * 32768;  // bytes per A/B double-buffer slot
    const u16* ga = Ag + t * 64;
    const u16* gb = Bg + t * 64;
#pragma unroll
    for (int h = 0; h < 4; ++h) {
      gload_lds16(ga + (size_t)h * 64 * KDIM, (char*)SM + ab + h * 8192 + tid * 16);
      gload_lds16(gb + (size_t)h * 64 * KDIM, (char*)SM + 65536 + ab + h * 8192 + tid * 16);
    }
  };

  stage(0, 0);

  for (int t = 0; t < NT; ++t) {
    const int buf = t & 1;
    if (t + 1 < NT) {
      stage(t + 1, buf ^ 1);
      asm volatile("s_waitcnt vmcnt(8)" ::: "memory");  // drain tile t, keep t+1
    } else {
      asm volatile("s_waitcnt vmcnt(0)" ::: "memory");
    }
    asm volatile("s_barrier" ::: "memory");  // all waves: tile t resident in LDS

    const int aB = aBase + buf * 16384;   // elements
    const int bB = bBase + buf * 16384;

    // B fragments once per tile (8 reads)
    bf16x8 bfr[4][2];
#pragma unroll
    for (int ni = 0; ni < 4; ++ni) {
      bfr[ni][0] = *(const bf16x8*)&SM[bB + ni * 1024 + kx0];
      bfr[ni][1] = *(const bf16x8*)&SM[bB + ni * 1024 + kx1];
    }
    // A fragments once per m-half (2 x 8 reads); MFMA over all 4 n-frags
#pragma unroll
    for (int qm = 0; qm < 2; ++qm) {
      bf16x8 af[4][2];
#pragma unroll
      for (int i = 0; i < 4; ++i) {
        const int mi = qm * 4 + i;
        af[i][0] = *(const bf16x8*)&SM[aB + mi * 1024 + kx0];
        af[i][1] = *(const bf16x8*)&SM[aB + mi * 1024 + kx1];
      }
      __builtin_amdgcn_s_setprio(1);
#pragma unroll
      for (int i = 0; i < 4; ++i)
#pragma unroll
        for (int ni = 0; ni < 4; ++ni) {
          acc[qm*4+i][ni] = __builtin_amdgcn_mfma_f32_16x16x32_bf16(
              af[i][0], bfr[ni][0], acc[qm*4+i][ni], 0, 0, 0);
          acc[qm*4+i][ni] = __builtin_amdgcn_mfma_f32_16x16x32_bf16(
              af[i][1], bfr[ni][1], acc[qm*4+i][ni], 0, 0, 0);
        }
      __builtin_amdgcn_s_setprio(0);
    }
    asm volatile("s_barrier" ::: "memory");  // reads done before buf reuse
  }

  const int cr = lg * 4, cc = l15;
#pragma unroll
  for (int mi = 0; mi < 8; ++mi)
#pragma unroll
    for (int j = 0; j < 4; ++j) {
      const int row = m0 + wm * 128 + mi * 16 + cr + j;
#pragma unroll
      for (int ni = 0; ni < 4; ++ni) {
        const int col = n0 + wn * 64 + ni * 16 + cc;
        C[(size_t)row * 1536 + col] = f2bf(acc[mi][ni][j]);
      }
    }
}

// ----------------------------------------------- 128x128 GEMM (output) ----
template <int N, bool OUT_F32>
__global__ __launch_bounds__(256) void gemm_bt(
    const u16* __restrict__ A, const u16* __restrict__ B,
    u16* __restrict__ Cb, float* __restrict__ Cf) {
  __shared__ __align__(16) u16 As[128 * 64];
  __shared__ __align__(16) u16 Bs[128 * 64];
  const int tid  = threadIdx.x;
  const int lane = tid & 63;
  const int wm = ((tid >> 6) >> 1) * 64;
  const int wn = ((tid >> 6) & 1) * 64;
  const int m0 = blockIdx.x * 128;
  const int n0 = blockIdx.y * 128;

  f32x4 acc[4][4] = {};

  const int rstg = tid >> 3;
  const int cstg = (tid & 7) * 8;
  const u16* Ag = A + (size_t)(m0 + rstg) * KDIM + cstg;
  const u16* Bg = B + (size_t)(n0 + rstg) * KDIM + cstg;
  char* AsB = (char*)As + tid * 16;
  char* BsB = (char*)Bs + tid * 16;

  for (int kt = 0; kt < KDIM; kt += 64) {
#pragma unroll
    for (int inst = 0; inst < 4; ++inst) {
      gload_lds16(Ag + (size_t)inst * 32 * KDIM + kt, AsB + inst * 4096);
      gload_lds16(Bg + (size_t)inst * 32 * KDIM + kt, BsB + inst * 4096);
    }
    __syncthreads();
#pragma unroll
    for (int kc = 0; kc < 2; ++kc) {
      const int ko = kc * 32 + (lane >> 4) * 8;
      bf16x8 af[4], bfr[4];
#pragma unroll
      for (int mi = 0; mi < 4; ++mi)
        af[mi] = *(const bf16x8*)&As[(wm + mi * 16 + (lane & 15)) * 64 + ko];
#pragma unroll
      for (int ni = 0; ni < 4; ++ni)
        bfr[ni] = *(const bf16x8*)&Bs[(wn + ni * 16 + (lane & 15)) * 64 + ko];
#pragma unroll
      for (int mi = 0; mi < 4; ++mi)
#pragma unroll
        for (int ni = 0; ni < 4; ++ni)
          acc[mi][ni] = __builtin_amdgcn_mfma_f32_16x16x32_bf16(
              af[mi], bfr[ni], acc[mi][ni], 0, 0, 0);
    }
    __syncthreads();
  }

  const int cr = (lane >> 4) * 4;
  const int cc = lane & 15;
#pragma unroll
  for (int mi = 0; mi < 4; ++mi) {
#pragma unroll
    for (int j = 0; j < 4; ++j) {
      const int row = m0 + wm + mi * 16 + cr + j;
      if (OUT_F32 && row >= M_REAL) continue;
#pragma unroll
      for (int ni = 0; ni < 4; ++ni) {
        const int col = n0 + wn + ni * 16 + cc;
        if constexpr (OUT_F32)
          Cf[(size_t)row * N + col] = acc[mi][ni][j];
        else
          Cb[(size_t)row * N + col] = f2bf(acc[mi][ni][j]);
      }
    }
  }
}

// ------------------------------------------------------------ attention ----
__global__ __launch_bounds__(256) void attn(const u16* __restrict__ QKV,
                                            u16* __restrict__ O,
                                            float* __restrict__ Part) {
  const int tid = threadIdx.x;
  if (blockIdx.x < NDB) {
    // ---- dense global-token row, chunk partials ----
    __shared__ float qs[64];
    __shared__ float ev[JC];
    __shared__ float red[256];
    const int db = blockIdx.x;
    const int b  = db / (8 * NCHUNK);
    const int rm = db % (8 * NCHUNK);
    const int h  = rm / NCHUNK;
    const int ch = rm % NCHUNK;
    const int j0 = ch * JC;
    const size_t base = (size_t)b * NNODE;

    if (tid < 64) qs[tid] = bf2f(QKV[base * 1536 + h * 64 + tid]);
    __syncthreads();

    const int j = j0 + tid;
    float s = -3e38f;
    if (j < NNODE) {
      const uint4* kp4 = (const uint4*)(QKV + (base + j) * 1536 + 512 + h * 64);
      float a = 0.f;
#pragma unroll
      for (int q8 = 0; q8 < 8; ++q8) {
        uint4 kv = kp4[q8];
        int d = q8 * 8;
        a += qs[d+0]*bflo(kv.x) + qs[d+1]*bfhi(kv.x)
           + qs[d+2]*bflo(kv.y) + qs[d+3]*bfhi(kv.y)
           + qs[d+4]*bflo(kv.z) + qs[d+5]*bfhi(kv.z)
           + qs[d+6]*bflo(kv.w) + qs[d+7]*bfhi(kv.w);
      }
      s = a * 0.125f;
    }
    red[tid] = s;
    __syncthreads();
    for (int st = 128; st > 0; st >>= 1) {
      if (tid < st) red[tid] = fmaxf(red[tid], red[tid + st]);
      __syncthreads();
    }
    const float mx = red[0];
    __syncthreads();
    const float e = (j < NNODE) ? __expf(s - mx) : 0.f;
    ev[tid] = e;
    red[tid] = e;
    __syncthreads();
    for (int st = 128; st > 0; st >>= 1) {
      if (tid < st) red[tid] += red[tid + st];
      __syncthreads();
    }
    const float ssum = red[0];
    __syncthreads();

    const int w = tid >> 6, lane = tid & 63;
    const int js = lane >> 3, dg = lane & 7;
    float oa[8] = {};
#pragma unroll
    for (int jj = 0; jj < 8; ++jj) {
      const int li = w * 64 + jj * 8 + js;
      const int jv = j0 + li;
      if (jv < NNODE) {
        const float we = ev[li];
        const uint4 vv = *(const uint4*)(QKV + (base + jv) * 1536 + 1024 + h * 64 + dg * 8);
        oa[0] += we * bflo(vv.x); oa[1] += we * bfhi(vv.x);
        oa[2] += we * bflo(vv.y); oa[3] += we * bfhi(vv.y);
        oa[4] += we * bflo(vv.z); oa[5] += we * bfhi(vv.z);
        oa[6] += we * bflo(vv.w); oa[7] += we * bfhi(vv.w);
      }
    }
#pragma unroll
    for (int m = 8; m <= 32; m <<= 1)
#pragma unroll
      for (int t = 0; t < 8; ++t) oa[t] += __shfl_xor(oa[t], m);
    __syncthreads();
    if (lane < 8) {
#pragma unroll
      for (int t = 0; t < 8; ++t) red[w * 64 + lane * 8 + t] = oa[t];
    }
    __syncthreads();
    float* P = Part + ((size_t)((b * 8 + h) * NCHUNK + ch)) * 66;
    if (tid == 0) { P[0] = mx; P[1] = ssum; }
    if (tid < 64)
      P[2 + tid] = red[tid] + red[64 + tid] + red[128 + tid] + red[192 + tid];
    return;
  }

  // ---- sparse rows: one wave per (b, node); XCD-chunked block swizzle ----
  const int obid = blockIdx.x - NDB;                    // 0..2047
  const int sb   = ((obid & 7) << 8) | (obid >> 3);     // bijective (2048 % 8 == 0)
  const int wid  = sb * 4 + (tid >> 6);                 // 0..8191
  const int lane = tid & 63;
  const int b = wid >> 12;
  const int g = wid & 4095;
  const int i = g + 1;
  const int r = g >> 6, c = g & 63;
  const size_t base = (size_t)b * NNODE;

  int  jn[6];
  bool vd[6];
  jn[0] = 0;                     vd[0] = true;
  jn[1] = i;                     vd[1] = true;
  jn[2] = (c > 0)  ? i - 1  : i; vd[2] = (c > 0);
  jn[3] = (c < 63) ? i + 1  : i; vd[3] = (c < 63);
  jn[4] = (r > 0)  ? i - 64 : i; vd[4] = (r > 0);
  jn[5] = (r < 63) ? i + 64 : i; vd[5] = (r < 63);

  const uint4 qv = *(const uint4*)(QKV + (base + i) * 1536 + lane * 8);
  float qf[8] = { bflo(qv.x), bfhi(qv.x), bflo(qv.y), bfhi(qv.y),
                  bflo(qv.z), bfhi(qv.z), bflo(qv.w), bfhi(qv.w) };

  float sc[6];
#pragma unroll
  for (int n = 0; n < 6; ++n) {
    const uint4 kv = *(const uint4*)(QKV + (base + jn[n]) * 1536 + 512 + lane * 8);
    float p = qf[0]*bflo(kv.x) + qf[1]*bfhi(kv.x)
            + qf[2]*bflo(kv.y) + qf[3]*bfhi(kv.y)
            + qf[4]*bflo(kv.z) + qf[5]*bfhi(kv.z)
            + qf[6]*bflo(kv.w) + qf[7]*bfhi(kv.w);
    p += __shfl_xor(p, 1);
    p += __shfl_xor(p, 2);
    p += __shfl_xor(p, 4);
    sc[n] = p * 0.125f;
  }
  float mx = -1e30f;
#pragma unroll
  for (int n = 0; n < 6; ++n) if (vd[n]) mx = fmaxf(mx, sc[n]);
  float pw[6], den = 0.f;
#pragma unroll
  for (int n = 0; n < 6; ++n) {
    pw[n] = vd[n] ? __expf(sc[n] - mx) : 0.f;
    den += pw[n];
  }
  const float inv = 1.f / den;

  float oa[8] = {};
#pragma unroll
  for (int n = 0; n < 6; ++n) {
    const uint4 vv = *(const uint4*)(QKV + (base + jn[n]) * 1536 + 1024 + lane * 8);
    const float w = pw[n];
    oa[0] += w * bflo(vv.x); oa[1] += w * bfhi(vv.x);
    oa[2] += w * bflo(vv.y); oa[3] += w * bfhi(vv.y);
    oa[4] += w * bflo(vv.z); oa[5] += w * bfhi(vv.z);
    oa[6] += w * bflo(vv.w); oa[7] += w * bfhi(vv.w);
  }
  uint4 ov;
  ov.x = (u32)f2bf(oa[0] * inv) | ((u32)f2bf(oa[1] * inv) << 16);
  ov.y = (u32)f2bf(oa[2] * inv) | ((u32)f2bf(oa[3] * inv) << 16);
  ov.z = (u32)f2bf(oa[4] * inv) | ((u32)f2bf(oa[5] * inv) << 16);
  ov.w = (u32)f2bf(oa[6] * inv) | ((u32)f2bf(oa[7] * inv) << 16);
  *(uint4*)(O + (base + i) * 512 + lane * 8) = ov;
}

// phase B: merge the NCHUNK partials per (b,h), write O row 0.
__global__ __launch_bounds__(64) void attn_fin(const float* __restrict__ Part,
                                               u16* __restrict__ O) {
  const int b = blockIdx.x >> 3, h = blockIdx.x & 7;
  const int d = threadIdx.x;
  const float* P = Part + ((size_t)(b * 8 + h) * NCHUNK) * 66;
  float m = -3e38f;
  for (int c = 0; c < NCHUNK; ++c) m = fmaxf(m, P[c * 66]);
  float s = 0.f, o = 0.f;
  for (int c = 0; c < NCHUNK; ++c) {
    const float ex = __expf(P[c * 66] - m);
    s += P[c * 66 + 1] * ex;
    o += P[c * 66 + 2 + d] * ex;
  }
  O[(size_t)b * NNODE * 512 + h * 64 + d] = f2bf(o / s);
}

// -------------------------------------------------------------- launch ----
extern "C" void kernel_launch(void* const* d_in, const int* in_sizes, int n_in,
                              void* d_out, int out_size, void* d_ws, size_t ws_size,
                              hipStream_t stream) {
  (void)in_sizes; (void)n_in; (void)out_size; (void)ws_size;
  const float* x  = (const float*)d_in[0];
  const float* wq = (const float*)d_in[1];
  const float* wk = (const float*)d_in[2];
  const float* wv = (const float*)d_in[3];
  const float* wo = (const float*)d_in[4];
  float* out = (float*)d_out;

  char* ws = (char*)d_ws;
  u16* Xp   = (u16*)ws;  ws += (size_t)M_PAD * 512 * 2;   //  8,650,752 B
  u16* Wqkv = (u16*)ws;  ws += (size_t)1536 * 512 * 2;    //  1,572,864 B
  u16* Wob  = (u16*)ws;  ws += (size_t)512 * 512 * 2;     //    524,288 B
  u16* QKV  = (u16*)ws;  ws += (size_t)M_PAD * 1536 * 2;  // 25,952,256 B
  u16* ATT  = (u16*)ws;                                   //  8,650,752 B
  float* Part = (float*)Xp;  // dead after gemm1; 272*66*4 = 72 KB

  prep<<<(NCH_X + NCH_WQ + NCH_WO) / 256, 256, 0, stream>>>(
      x, wq, wk, wv, wo, Xp, Wqkv, Wob);

  dim3 g1(M_PAD / 256, 1536 / 256);
  gemm256<<<g1, 512, 0, stream>>>(Xp, Wqkv, QKV);

  attn<<<NDB + 2048, 256, 0, stream>>>(QKV, ATT, Part);
  attn_fin<<<16, 64, 0, stream>>>(Part, ATT);

  dim3 g2(M_PAD / 128, 512 / 128);
  gemm_bt<512, true><<<g2, 256, 0, stream>>>(ATT, Wob, nullptr, out);
}